// Round 5
// baseline (40.775 us; speedup 1.0000x reference)
//
#include <hip/hip_runtime.h>
#include <hip/hip_bf16.h>

#define B_    2048
#define OBS_  1024
#define A_    512

typedef __attribute__((ext_vector_type(8))) short bf16x8;
typedef __attribute__((ext_vector_type(4))) float f32x4;

__device__ __forceinline__ float fast_tanh(float x) {
    return 1.0f - 2.0f / (__expf(2.0f * x) + 1.0f);
}

__device__ __forceinline__ unsigned short rne_bf16(float f) {
    union { float f; unsigned u; } v; v.f = f;
    unsigned u = v.u;
    return (unsigned short)((u + 0x7FFFu + ((u >> 16) & 1u)) >> 16);
}

__device__ __forceinline__ unsigned pack2_bf16(float lo, float hi) {
    return (unsigned)rne_bf16(lo) | ((unsigned)rne_bf16(hi) << 16);
}

__device__ __forceinline__ short to_bf16(float f) {
    __hip_bfloat16 h = __float2bfloat16(f);
    return *reinterpret_cast<short*>(&h);
}

// broadcast register value from lane k (compile-time k) via SGPR
#define RL(x, k) __int_as_float(__builtin_amdgcn_readlane(__float_as_int(x), (k)))

// ws layout (bytes)
#define WS_WFRAG   0          // 131072 bf16 = 262144 B
#define WS_W2F     262144     // 4096 bf16 = 8192 B
#define WS_WFF     270336
#define WS_WC2F    278528
#define WS_VTP     286720     // 2048 u32 = 8192 B

// ---------------- Kernel 0: weight prep into MFMA fragment layouts ------------
// Wfrag [ks(32)][ntile(8)][lane(64)][i(8)]: k=ks*32+(l>>4)*8+i, n=ntile*16+(l&15)
// 64x64 frags [ks(2)][nt(4)][lane(64)][i(8)] for W2/Wf/Wc2
// vTp [hp(32)][t(64)] bf16x2 = (embWe[t][2hp], embWe[t][2hp+1])
__global__ __launch_bounds__(256) void k0_prep(
        const float* __restrict__ W1, const float* __restrict__ Wc1,
        const float* __restrict__ emb, const float* __restrict__ We,
        const float* __restrict__ W2, const float* __restrict__ Wf,
        const float* __restrict__ Wc2, unsigned char* __restrict__ ws) {
    const int bid = blockIdx.x, tid = threadIdx.x;
    if (bid < 512) {
        unsigned short* Wfrag = (unsigned short*)(ws + WS_WFRAG);
        int gid   = bid * 256 + tid;
        int i     = gid & 7;
        int lane  = (gid >> 3) & 63;
        int ntile = (gid >> 9) & 7;
        int ks    = gid >> 12;
        int k = ks * 32 + ((lane >> 4) << 3) + i;
        int n = ntile * 16 + (lane & 15);
        float w = (n < 64) ? W1[(size_t)k * 64 + n] : Wc1[(size_t)k * 64 + (n - 64)];
        Wfrag[gid] = rne_bf16(w);
    } else if (bid < 515) {
        int sec = bid - 512;  // 0:W2 1:Wf 2:Wc2
        const float* src = (sec == 0) ? W2 : (sec == 1) ? Wf : Wc2;
        unsigned short* dst = (unsigned short*)(ws + WS_W2F + sec * 8192);
        #pragma unroll
        for (int e = 0; e < 16; ++e) {
            int gid2 = tid + e * 256;          // 0..4095
            int i    = gid2 & 7;
            int lane = (gid2 >> 3) & 63;
            int nt   = (gid2 >> 9) & 3;
            int ks   = gid2 >> 11;
            int k = ks * 32 + ((lane >> 4) << 3) + i;
            int n = nt * 16 + (lane & 15);
            dst[gid2] = rne_bf16(src[k * 64 + n]);
        }
    } else {
        unsigned* vTp = (unsigned*)(ws + WS_VTP);
        #pragma unroll
        for (int e = 0; e < 8; ++e) {
            int idx = tid + e * 256;           // 0..2047
            int hp = idx >> 6, t = idx & 63;
            float s0 = 0.f, s1 = 0.f;
            #pragma unroll
            for (int q = 0; q < 16; ++q) {
                float ev = emb[t * 16 + q];
                s0 += ev * We[q * 64 + 2 * hp];
                s1 += ev * We[q * 64 + 2 * hp + 1];
            }
            vTp[idx] = pack2_bf16(s0, s1);
        }
    }
}

// ---------------- Fused kernel: 8 batch rows per block, everything in-block ---
__global__ __launch_bounds__(256) void k_fused(
        const float* __restrict__ x, const unsigned char* __restrict__ ws,
        const int* __restrict__ action_types, const int* __restrict__ action_counts,
        const int* __restrict__ action,
        const float* __restrict__ b1, const float* __restrict__ bc1,
        const float* __restrict__ b2, const float* __restrict__ ba,
        const float* __restrict__ Wo, const float* __restrict__ bo,
        const float* __restrict__ bc2, const float* __restrict__ Wc3,
        const float* __restrict__ bc3, float* __restrict__ out) {
    __shared__ __align__(16) unsigned short sHID[16 * 136]; // [row][col0..127] pad to 136
    __shared__ __align__(16) unsigned short sF[16 * 72];    // feats bf16 [row][0..63] pad 72
    __shared__ __align__(16) float sU[16 * 68];             // u f32 [row][0..63] pad 68
    __shared__ unsigned sVT[2048];                          // vT packed bf16x2 [hp][t]
    __shared__ int scnt[4][64];
    __shared__ float vsum[16];

    const int tid = threadIdx.x;
    const int w   = tid >> 6;      // wave 0..3
    const int l   = tid & 63;
    const int mb  = blockIdx.x;    // rows mb*8 .. mb*8+7

    // stage vT table; zero vsum
    {
        const unsigned* vTp = (const unsigned*)(ws + WS_VTP);
        #pragma unroll
        for (int e = 0; e < 8; ++e) sVT[tid + e * 256] = vTp[tid + e * 256];
        if (tid < 16) vsum[tid] = 0.f;
    }

    // ---------------- GEMM1: x[8 rows] @ [W1|Wc1] -> sHID ----------------
    const int rl   = (l & 15) & 7;            // duplicate rows 0-7 for lanes 8-15
    const int kgrp = (l >> 4) << 3;
    const float* xrow = x + (size_t)(mb * 8 + rl) * OBS_;
    const bf16x8* Wf8 = (const bf16x8*)(ws + WS_WFRAG);

    f32x4 acc0 = {0.f, 0.f, 0.f, 0.f};
    f32x4 acc1 = {0.f, 0.f, 0.f, 0.f};
    const int nt0 = w * 2, nt1 = w * 2 + 1;
    #pragma unroll 4
    for (int ks = 0; ks < 32; ++ks) {
        const float4* xp = (const float4*)(xrow + ks * 32 + kgrp);
        float4 a0 = xp[0];
        float4 a1 = xp[1];
        bf16x8 av;
        av[0] = to_bf16(a0.x); av[1] = to_bf16(a0.y);
        av[2] = to_bf16(a0.z); av[3] = to_bf16(a0.w);
        av[4] = to_bf16(a1.x); av[5] = to_bf16(a1.y);
        av[6] = to_bf16(a1.z); av[7] = to_bf16(a1.w);
        bf16x8 bv0 = Wf8[(ks * 8 + nt0) * 64 + l];
        bf16x8 bv1 = Wf8[(ks * 8 + nt1) * 64 + l];
        acc0 = __builtin_amdgcn_mfma_f32_16x16x32_bf16(av, bv0, acc0, 0, 0, 0);
        acc1 = __builtin_amdgcn_mfma_f32_16x16x32_bf16(av, bv1, acc1, 0, 0, 0);
    }
    // D: col = l&15 (+16*nt), row = (l>>4)*4 + j
    {
        const int g = l >> 4;
        int col0 = w * 32 + (l & 15);
        int col1 = col0 + 16;
        float bias0 = (col0 < 64) ? b1[col0] : bc1[col0 - 64];
        float bias1 = (col1 < 64) ? b1[col1] : bc1[col1 - 64];
        #pragma unroll
        for (int j = 0; j < 4; ++j) {
            sHID[(4 * g + j) * 136 + col0] = (unsigned short)to_bf16(fast_tanh(acc0[j] + bias0));
            sHID[(4 * g + j) * 136 + col1] = (unsigned short)to_bf16(fast_tanh(acc1[j] + bias1));
        }
    }
    __syncthreads();

    // ---------------- GEMM2: feats = tanh(h1 @ W2 + b2) -> sF --------------
    const bf16x8* W2f8  = (const bf16x8*)(ws + WS_W2F);
    const bf16x8* Wff8  = (const bf16x8*)(ws + WS_WFF);
    const bf16x8* Wc2f8 = (const bf16x8*)(ws + WS_WC2F);
    const int g = l >> 4;
    const int colh = w * 16 + (l & 15);       // this wave's head col
    {
        f32x4 d = {0.f, 0.f, 0.f, 0.f};
        #pragma unroll
        for (int ks = 0; ks < 2; ++ks) {
            bf16x8 a = *(const bf16x8*)&sHID[(l & 15) * 136 + ks * 32 + kgrp];
            bf16x8 bv = W2f8[(ks * 4 + w) * 64 + l];
            d = __builtin_amdgcn_mfma_f32_16x16x32_bf16(a, bv, d, 0, 0, 0);
        }
        float bias = b2[colh];
        #pragma unroll
        for (int j = 0; j < 4; ++j)
            sF[(4 * g + j) * 72 + colh] = (unsigned short)to_bf16(fast_tanh(d[j] + bias));
    }
    __syncthreads();

    // ---------------- GEMM3: u = feats @ Wf + ba -> sU ----------------------
    {
        f32x4 d = {0.f, 0.f, 0.f, 0.f};
        #pragma unroll
        for (int ks = 0; ks < 2; ++ks) {
            bf16x8 a = *(const bf16x8*)&sF[(l & 15) * 72 + ks * 32 + kgrp];
            bf16x8 bv = Wff8[(ks * 4 + w) * 64 + l];
            d = __builtin_amdgcn_mfma_f32_16x16x32_bf16(a, bv, d, 0, 0, 0);
        }
        float bias = ba[colh];
        #pragma unroll
        for (int j = 0; j < 4; ++j)
            sU[(4 * g + j) * 68 + colh] = d[j] + bias;
    }
    // ---------------- critic: cc = tanh(c1 @ Wc2 + bc2); vsum += cc*Wc3 -----
    {
        f32x4 d = {0.f, 0.f, 0.f, 0.f};
        #pragma unroll
        for (int ks = 0; ks < 2; ++ks) {
            bf16x8 a = *(const bf16x8*)&sHID[(l & 15) * 136 + 64 + ks * 32 + kgrp];
            bf16x8 bv = Wc2f8[(ks * 4 + w) * 64 + l];
            d = __builtin_amdgcn_mfma_f32_16x16x32_bf16(a, bv, d, 0, 0, 0);
        }
        float bias = bc2[colh];
        float wc3  = Wc3[colh];
        #pragma unroll
        for (int j = 0; j < 4; ++j) {
            float pv = fast_tanh(d[j] + bias) * wc3;
            pv += __shfl_xor(pv, 1);
            pv += __shfl_xor(pv, 2);
            pv += __shfl_xor(pv, 4);
            pv += __shfl_xor(pv, 8);
            if ((l & 15) == 0) atomicAdd(&vsum[4 * g + j], pv);
        }
    }
    __syncthreads();

    // ---------------- score + softmax + histogram: 2 rows per wave ----------
    const float bo_v  = bo[0];
    const float bc3_v = bc3[0];
    int* cptr = scnt[w];
    #pragma unroll
    for (int rr = 0; rr < 2; ++rr) {
        const int r = w * 2 + rr;
        const int b = mb * 8 + r;

        // issue action-data loads early
        const int* at_row = action_types + (size_t)b * A_;
        const int count = action_counts[b];
        const int base  = l * 8;
        int4 p0 = *reinterpret_cast<const int4*>(at_row + base);
        int4 p1 = *reinterpret_cast<const int4*>(at_row + base + 4);
        const int a_star = action[b];
        const int t_star = at_row[a_star] & 63;

        const float uv = sU[r * 68 + l];     // u[r][lane]
        // s[t] for t = lane
        float s = bo_v;
        #pragma unroll
        for (int hp = 0; hp < 32; ++hp) {
            unsigned pvv = sVT[hp * 64 + l];
            s += fast_tanh(RL(uv, 2 * hp)     + __uint_as_float(pvv << 16))         * Wo[2 * hp];
            s += fast_tanh(RL(uv, 2 * hp + 1) + __uint_as_float(pvv & 0xffff0000u)) * Wo[2 * hp + 1];
        }

        // wave-private histogram
        cptr[l] = 0;
        if (base + 0 < count) atomicAdd(&cptr[p0.x & 63], 1);
        if (base + 1 < count) atomicAdd(&cptr[p0.y & 63], 1);
        if (base + 2 < count) atomicAdd(&cptr[p0.z & 63], 1);
        if (base + 3 < count) atomicAdd(&cptr[p0.w & 63], 1);
        if (base + 4 < count) atomicAdd(&cptr[p1.x & 63], 1);
        if (base + 5 < count) atomicAdd(&cptr[p1.y & 63], 1);
        if (base + 6 < count) atomicAdd(&cptr[p1.z & 63], 1);
        if (base + 7 < count) atomicAdd(&cptr[p1.w & 63], 1);

        const int cv = cptr[l];
        float mval = (cv > 0) ? s : -3.0e38f;
        #pragma unroll
        for (int off = 32; off > 0; off >>= 1) mval = fmaxf(mval, __shfl_xor(mval, off));
        const float e  = (float)cv * __expf(s - mval);
        float se = e, sd = e * s;
        #pragma unroll
        for (int off = 32; off > 0; off >>= 1) {
            se += __shfl_xor(se, off);
            sd += __shfl_xor(sd, off);
        }
        const float logZ    = mval + __logf(se);
        const float entropy = logZ - sd / se;
        const float logp    = __shfl(s, t_star) - logZ;

        if (l == 0) {
            out[b * 3 + 0] = logp;
            out[b * 3 + 1] = entropy;
            out[b * 3 + 2] = vsum[r] + bc3_v;
        }
    }
}

extern "C" void kernel_launch(void* const* d_in, const int* in_sizes, int n_in,
                              void* d_out, int out_size, void* d_ws, size_t ws_size,
                              hipStream_t stream) {
    const float* x             = (const float*)d_in[0];
    const int*   action_types  = (const int*)  d_in[1];
    const int*   action_counts = (const int*)  d_in[2];
    const int*   action        = (const int*)  d_in[3];
    const float* emb           = (const float*)d_in[4];
    const float* W1            = (const float*)d_in[5];
    const float* b1            = (const float*)d_in[6];
    const float* W2            = (const float*)d_in[7];
    const float* b2            = (const float*)d_in[8];
    const float* Wf            = (const float*)d_in[9];
    const float* We            = (const float*)d_in[10];
    const float* ba            = (const float*)d_in[11];
    const float* Wo            = (const float*)d_in[12];
    const float* bo            = (const float*)d_in[13];
    const float* Wc1           = (const float*)d_in[14];
    const float* bc1           = (const float*)d_in[15];
    const float* Wc2           = (const float*)d_in[16];
    const float* bc2           = (const float*)d_in[17];
    const float* Wc3           = (const float*)d_in[18];
    const float* bc3           = (const float*)d_in[19];
    float* out = (float*)d_out;
    unsigned char* ws = (unsigned char*)d_ws;

    k0_prep<<<516, 256, 0, stream>>>(W1, Wc1, emb, We, W2, Wf, Wc2, ws);
    k_fused<<<256, 256, 0, stream>>>(x, ws, action_types, action_counts, action,
                                     b1, bc1, b2, ba, Wo, bo, bc2, Wc3, bc3, out);
}